// Round 8
// baseline (2376.811 us; speedup 1.0000x reference)
//
#include <hip/hip_runtime.h>
#include <math.h>
#include <float.h>

#define BN_EPS 1e-5f
#define WB 240   // worker blocks (blockIdx 16..255)
#define FB 16    // fps blocks   (blockIdx 0..15)
#define TPB 512

// Exact (non-contracted) squared distance: matches numpy mul-then-add order.
__device__ __forceinline__ float sqdist_exact(float dx, float dy, float dz) {
  return __fadd_rn(__fadd_rn(__fmul_rn(dx, dx), __fmul_rn(dy, dy)), __fmul_rn(dz, dz));
}

// Key = (float_bits(dist) << 32) | ~index : max key == max dist, first-index ties.
#define DPP_STEP(CTRL)                                                                   \
  {                                                                                      \
    unsigned int nhi = (unsigned int)__builtin_amdgcn_update_dpp((int)khi, (int)khi,     \
                                                                 CTRL, 0xf, 0xf, false); \
    unsigned int nlo = (unsigned int)__builtin_amdgcn_update_dpp((int)klo, (int)klo,     \
                                                                 CTRL, 0xf, 0xf, false); \
    unsigned long long nk = (((unsigned long long)nhi) << 32) | nlo;                     \
    if (nk > wk) { wk = nk; khi = nhi; klo = nlo; }                                      \
  }

struct MegaParams {
  const float* x;
  const float *W1, *g1, *b1;
  const float *W2, *g2, *b2;
  const float *W3, *g3, *b3;
  const float *W4, *g4, *b4;
  const float *W5, *g5, *b5;
  float *HA, *HB, *YMIN;
  float *NP1, *NP2, *NP3, *NP4;
  int *NIDX1, *NIDX2, *NIDX3, *NIDX4;
  float* PART;  // 5 stages x 65536 floats, 64 slots x 2*D each
  int* SYNC;    // [0..3] np flags, [4..19] barrier counters
};

__device__ __forceinline__ void worker_bar(int* cnt, int phase, int t) {
  __syncthreads();  // drain this block's stores (s_waitcnt before s_barrier)
  if (t == 0) {
    __threadfence();
    __hip_atomic_fetch_add(&cnt[phase], 1, __ATOMIC_RELEASE, __HIP_MEMORY_SCOPE_AGENT);
    while (__hip_atomic_load(&cnt[phase], __ATOMIC_ACQUIRE, __HIP_MEMORY_SCOPE_AGENT) < WB)
      __builtin_amdgcn_s_sleep(16);
  }
  __syncthreads();
}

__device__ __forceinline__ void wait_np(int* np, int k, int t) {
  if (t == 0)
    while (__hip_atomic_load(&np[k], __ATOMIC_ACQUIRE, __HIP_MEMORY_SCOPE_AGENT) < FB)
      __builtin_amdgcn_s_sleep(16);
  __syncthreads();
}

// ---- single-wave FPS (stages 2-4), src points in LDS, coords via readlane ----
template <int PP>
__device__ void fps_w0(const float* src, float* dstG, float* dstL, int lane, int* flag) {
  constexpr int N = PP * 64, M = N / 4;
  float px[PP], py[PP], pz[PP], md[PP];
#pragma unroll
  for (int j = 0; j < PP; j++) {
    int i = j * 64 + lane;
    px[j] = src[3 * i]; py[j] = src[3 * i + 1]; pz[j] = src[3 * i + 2];
    md[j] = INFINITY;
  }
  float lx = src[0], ly = src[1], lz = src[2];
  if (lane == 0) {
    dstG[0] = lx; dstG[1] = ly; dstG[2] = lz;
    if (dstL) { dstL[0] = lx; dstL[1] = ly; dstL[2] = lz; }
  }
  for (int r = 1; r < M; r++) {
    float bv, bx, by, bz; int bi;
    {
      float d0 = sqdist_exact(px[0] - lx, py[0] - ly, pz[0] - lz);
      float m0 = fminf(md[0], d0);
      md[0] = m0;
      bv = m0; bi = lane; bx = px[0]; by = py[0]; bz = pz[0];
    }
#pragma unroll
    for (int j = 1; j < PP; j++) {
      float d = sqdist_exact(px[j] - lx, py[j] - ly, pz[j] - lz);
      float m = fminf(md[j], d);
      md[j] = m;
      if (m > bv) { bv = m; bi = j * 64 + lane; bx = px[j]; by = py[j]; bz = pz[j]; }
    }
    unsigned int khi = __float_as_uint(bv);
    unsigned int klo = ~(unsigned int)bi;
    unsigned long long wk = (((unsigned long long)khi) << 32) | klo;
    DPP_STEP(0x111); DPP_STEP(0x112); DPP_STEP(0x114);
    DPP_STEP(0x118); DPP_STEP(0x142); DPP_STEP(0x143);
    unsigned int wlo = (unsigned int)__builtin_amdgcn_readlane((int)wk, 63);
    int owner = (int)((~wlo) & 63u);
    lx = __int_as_float(__builtin_amdgcn_readlane(__float_as_int(bx), owner));
    ly = __int_as_float(__builtin_amdgcn_readlane(__float_as_int(by), owner));
    lz = __int_as_float(__builtin_amdgcn_readlane(__float_as_int(bz), owner));
    if (lane == 0) {
      dstG[3 * r] = lx; dstG[3 * r + 1] = ly; dstG[3 * r + 2] = lz;
      if (dstL) { dstL[3 * r] = lx; dstL[3 * r + 1] = ly; dstL[3 * r + 2] = lz; }
    }
  }
  if (lane == 0) {
    __threadfence();
    __hip_atomic_fetch_add(flag, 1, __ATOMIC_RELEASE, __HIP_MEMORY_SCOPE_AGENT);
  }
}

// ---- FPS role: stage1 = fps4 (measured best), then stages 2-4 on wave 0 ----
__device__ void fps_role(const MegaParams& P, float* smem, int b, int t) {
  constexpr int P1 = 8, BS = 512, N1 = 4096, M1 = 1024;
  float* spts = smem;            // 12288 floats
  float* snew = smem + 12288;    // 3072 floats (NP1 copy)
  unsigned long long* slots = (unsigned long long*)(smem + 15360);  // 16 u64
  const int wv = t >> 6, lane = t & 63;
  const float* pb = P.x + (size_t)b * N1 * 3;
  float px[P1], py[P1], pz[P1], md[P1];
#pragma unroll
  for (int j = 0; j < P1; j++) {
    int i = j * BS + t;
    float xx = pb[3 * i], yy = pb[3 * i + 1], zz = pb[3 * i + 2];
    px[j] = xx; py[j] = yy; pz[j] = zz; md[j] = INFINITY;
    spts[3 * i] = xx; spts[3 * i + 1] = yy; spts[3 * i + 2] = zz;
  }
  float lx = pb[0], ly = pb[1], lz = pb[2];
  if (t == 0) { snew[0] = lx; snew[1] = ly; snew[2] = lz; }

  for (int r = 1; r < M1; r++) {
    float bv; int bi;
    {
      float d0 = sqdist_exact(px[0] - lx, py[0] - ly, pz[0] - lz);
      float m0 = fminf(md[0], d0);
      md[0] = m0;
      bv = m0; bi = t;
    }
#pragma unroll
    for (int j = 1; j < P1; j++) {
      float d = sqdist_exact(px[j] - lx, py[j] - ly, pz[j] - lz);
      float m = fminf(md[j], d);
      md[j] = m;
      if (m > bv) { bv = m; bi = j * BS + t; }
    }
    unsigned int khi = __float_as_uint(bv);
    unsigned int klo = ~(unsigned int)bi;
    unsigned long long wk = (((unsigned long long)khi) << 32) | klo;
    DPP_STEP(0x111); DPP_STEP(0x112); DPP_STEP(0x114);
    DPP_STEP(0x118); DPP_STEP(0x142); DPP_STEP(0x143);
    unsigned long long* base = slots + (r & 1) * 8;
    if (lane == 63) base[wv] = wk;
    __syncthreads();
    unsigned long long fk = base[0];
#pragma unroll
    for (int w = 1; w < 8; w++) {
      unsigned long long k2 = base[w];
      if (k2 > fk) fk = k2;
    }
    unsigned int gidx = ~(unsigned int)fk;
    lx = spts[3 * gidx]; ly = spts[3 * gidx + 1]; lz = spts[3 * gidx + 2];
    if (t == 0) { snew[3 * r] = lx; snew[3 * r + 1] = ly; snew[3 * r + 2] = lz; }
  }
  __syncthreads();
  for (int i = t; i < M1 * 3; i += BS) P.NP1[(size_t)b * M1 * 3 + i] = snew[i];
  __syncthreads();  // drain all waves' NP1 stores
  if (t == 0) {
    __threadfence();
    __hip_atomic_fetch_add(&P.SYNC[0], 1, __ATOMIC_RELEASE, __HIP_MEMORY_SCOPE_AGENT);
  }
  // stages 2-4: wave 0 only, inputs from LDS copies (spts area is dead; snew holds NP1)
  if (t < 64) {
    float* snewB = smem;          // 768 floats (NP2 copy)
    float* snewC = smem + 1024;   // 192 floats (NP3 copy)
    fps_w0<16>(snew, P.NP2 + (size_t)b * 256 * 3, snewB, lane, &P.SYNC[1]);
    fps_w0<4>(snewB, P.NP3 + (size_t)b * 64 * 3, snewC, lane, &P.SYNC[2]);
    fps_w0<1>(snewC, P.NP4 + (size_t)b * 16 * 3, (float*)0, lane, &P.SYNC[3]);
  }
}

// ---- worker: mlp1 + fused per-channel stats ----
__device__ void mlp_w(const MegaParams& P, float* smem, int wid, int t, int bslot) {
  float s = 0.f, q = 0.f;
  int tid0 = wid * TPB + t;
  int d0 = tid0 & 31;
  for (int i = tid0; i < 65536 * 32; i += WB * TPB) {
    int row = i >> 5, d = i & 31;
    float x0 = P.x[row * 3], x1 = P.x[row * 3 + 1], x2 = P.x[row * 3 + 2];
    float a = x0 * P.W1[d] + x1 * P.W1[32 + d] + x2 * P.W1[64 + d];
    P.HA[i] = a; s += a; q += a * a;
  }
  float* sm2 = smem;  // 64 floats
  for (int i = t; i < 64; i += TPB) sm2[i] = 0.f;
  __syncthreads();
  atomicAdd(&sm2[d0], s);
  atomicAdd(&sm2[32 + d0], q);
  __syncthreads();
  for (int i = t; i < 64; i += TPB) atomicAdd(&P.PART[bslot * 64 + i], sm2[i]);
}

// ---- worker: compute BN scale/shift into LDS from PART slots ----
__device__ void ss_compute(const float* partial, const float* g, const float* bb,
                           float cnt, int D, float* ssl, int t) {
  for (int d = t; d < D; d += TPB) {
    float s = 0.f, q = 0.f;
    for (int j = 0; j < 64; j++) { s += partial[j * 2 * D + d]; q += partial[j * 2 * D + D + d]; }
    float mean = s / cnt;
    float var = fmaxf(q / cnt - mean * mean, 0.f);
    float sc = g[d] * rsqrtf(var + BN_EPS);
    ssl[d] = sc; ssl[D + d] = bb[d] - mean * sc;
  }
  __syncthreads();
}

__device__ void bn_w(float* vmax, const float* vmin, const float* ssl, int D, int n,
                     int wid, int t) {
  for (int i = wid * TPB + t; i < n; i += WB * TPB) {
    int d = i & (D - 1);
    float sc = ssl[d], sh = ssl[D + d];
    float v = (sc >= 0.f) ? vmax[i] : vmin[i];
    vmax[i] = fmaxf(v * sc + sh, 0.f);
  }
}

// ---- worker: KNN, one wave per query ----
__device__ void knn_w(const float* p, const float* newp, int N, int M, int BM,
                      int* nidx, int wid, int t) {
  int gw = wid * 8 + (t >> 6);
  int lane = t & 63;
  for (int q = gw; q < BM; q += WB * 8) {
    int b = q / M;
    const float* pb = p + (size_t)b * N * 3;
    float qx = newp[(size_t)q * 3], qy = newp[(size_t)q * 3 + 1], qz = newp[(size_t)q * 3 + 2];
    float bd[16]; int bi[16];
#pragma unroll
    for (int s = 0; s < 16; s++) { bd[s] = INFINITY; bi[s] = 0x7FFFFFFF; }
    for (int c = lane; c < N; c += 64) {
      float d = sqdist_exact(pb[3 * c] - qx, pb[3 * c + 1] - qy, pb[3 * c + 2] - qz);
      if (d < bd[15]) {
        bd[15] = d; bi[15] = c;
#pragma unroll
        for (int s = 15; s >= 1; --s) {
          if (bd[s] < bd[s - 1]) {
            float tf = bd[s]; bd[s] = bd[s - 1]; bd[s - 1] = tf;
            int ti = bi[s]; bi[s] = bi[s - 1]; bi[s - 1] = ti;
          }
        }
      }
    }
    int out = 0;
    for (int r = 0; r < 16; r++) {
      float v = bd[0]; int ii = bi[0];
      float mv = v; int mi = ii;
#pragma unroll
      for (int m = 1; m < 64; m <<= 1) {
        float v2 = __shfl_xor(mv, m);
        int i2 = __shfl_xor(mi, m);
        if (v2 < mv || (v2 == mv && i2 < mi)) { mv = v2; mi = i2; }
      }
      if (mi == ii) {
#pragma unroll
        for (int s = 0; s < 15; s++) { bd[s] = bd[s + 1]; bi[s] = bi[s + 1]; }
        bd[15] = INFINITY; bi[15] = 0x7FFFFFFF;
      }
      if (lane == r) out = mi;
    }
    if (lane < 16) nidx[(size_t)q * 16 + lane] = out;
  }
}

// ---- worker: gather + GEMM + stats + max/min pool ----
__device__ void gemm_w(const float* p, const float* h, const float* newp,
                       const int* nidx, const float* W,
                       float* ymax, float* ymin, float* partial,
                       int N, int M, int BM, int Ch, int Cpad, int D,
                       int wid, int t, float* smem, int bslot) {
  int Ctot = Ch + 3;
  int Gpar = TPB / D;  // D in {64,128,256,512}
  float* sfeat = smem;          // Gpar*16*Cpad <= 4608 floats
  float* sstat = smem + 8192;   // 2*D
  for (int i = t; i < 2 * D; i += TPB) sstat[i] = 0.f;
  int mloc = t / D;
  int d = t % D;
  __syncthreads();
  for (int grp0 = wid * Gpar; grp0 < BM; grp0 += WB * Gpar) {
    int nf = Gpar * 16 * Cpad;
    for (int i = t; i < nf; i += TPB) {
      int c = i % Cpad;
      int rk = i / Cpad;
      int k = rk & 15;
      int g = rk >> 4;
      int grp = grp0 + g;
      float val = 0.f;
      if (grp < BM && c < Ctot) {
        int b = grp / M;
        int nb = nidx[(size_t)grp * 16 + k];
        if (c < 3)
          val = p[((size_t)b * N + nb) * 3 + c] - newp[(size_t)grp * 3 + c];
        else
          val = h[((size_t)b * N + nb) * Ch + (c - 3)];
      }
      sfeat[i] = val;
    }
    __syncthreads();
    int grp = grp0 + mloc;
    bool act = grp < BM;
    const float* fr = sfeat + mloc * 16 * Cpad;
    float acc[16];
#pragma unroll
    for (int k = 0; k < 16; k++) acc[k] = 0.f;
    for (int c = 0; c < Cpad; c += 4) {
      float w0 = (c < Ctot) ? W[(size_t)c * D + d] : 0.f;
      float w1 = (c + 1 < Ctot) ? W[(size_t)(c + 1) * D + d] : 0.f;
      float w2 = (c + 2 < Ctot) ? W[(size_t)(c + 2) * D + d] : 0.f;
      float w3 = (c + 3 < Ctot) ? W[(size_t)(c + 3) * D + d] : 0.f;
#pragma unroll
      for (int k = 0; k < 16; k++) {
        const float4 f = *reinterpret_cast<const float4*>(fr + k * Cpad + c);
        acc[k] += f.x * w0 + f.y * w1 + f.z * w2 + f.w * w3;
      }
    }
    if (act) {
      float ssum = 0.f, ssq = 0.f, amax = -INFINITY, amin = INFINITY;
#pragma unroll
      for (int k = 0; k < 16; k++) {
        float a = acc[k];
        ssum += a; ssq += a * a;
        amax = fmaxf(amax, a); amin = fminf(amin, a);
      }
      ymax[(size_t)grp * D + d] = amax;
      ymin[(size_t)grp * D + d] = amin;
      atomicAdd(&sstat[d], ssum);
      atomicAdd(&sstat[D + d], ssq);
    }
    __syncthreads();
  }
  for (int i = t; i < 2 * D; i += TPB)
    atomicAdd(&partial[bslot * 2 * D + i], sstat[i]);
}

__device__ void worker_role(const MegaParams& P, float* smem, int wid, int t, int bslot) {
  int* np = P.SYNC;
  int* cnt = P.SYNC + 4;
  float* ssl = smem;  // BN scale/shift (<=1024 floats); disjoint phases

  mlp_w(P, smem, wid, t, bslot);
  worker_bar(cnt, 0, t);
  ss_compute(P.PART, P.g1, P.b1, 65536.f, 32, ssl, t);  // count = rows (B*N), not elements!
  bn_w(P.HA, P.HA, ssl, 32, 65536 * 32, wid, t);
  worker_bar(cnt, 1, t);

  wait_np(np, 0, t);
  knn_w(P.x, P.NP1, 4096, 1024, 16384, P.NIDX1, wid, t);
  worker_bar(cnt, 2, t);
  gemm_w(P.x, P.HA, P.NP1, P.NIDX1, P.W2, P.HB, P.YMIN, P.PART + 65536,
         4096, 1024, 16384, 32, 36, 64, wid, t, smem, bslot);
  worker_bar(cnt, 3, t);

  ss_compute(P.PART + 65536, P.g2, P.b2, (float)(16384 * 16), 64, ssl, t);
  bn_w(P.HB, P.YMIN, ssl, 64, 16384 * 64, wid, t);
  wait_np(np, 1, t);
  knn_w(P.NP1, P.NP2, 1024, 256, 4096, P.NIDX2, wid, t);
  worker_bar(cnt, 4, t);
  gemm_w(P.NP1, P.HB, P.NP2, P.NIDX2, P.W3, P.HA, P.YMIN, P.PART + 2 * 65536,
         1024, 256, 4096, 64, 68, 128, wid, t, smem, bslot);
  worker_bar(cnt, 5, t);

  ss_compute(P.PART + 2 * 65536, P.g3, P.b3, (float)(4096 * 16), 128, ssl, t);
  bn_w(P.HA, P.YMIN, ssl, 128, 4096 * 128, wid, t);
  wait_np(np, 2, t);
  knn_w(P.NP2, P.NP3, 256, 64, 1024, P.NIDX3, wid, t);
  worker_bar(cnt, 6, t);
  gemm_w(P.NP2, P.HA, P.NP3, P.NIDX3, P.W4, P.HB, P.YMIN, P.PART + 3 * 65536,
         256, 64, 1024, 128, 132, 256, wid, t, smem, bslot);
  worker_bar(cnt, 7, t);

  ss_compute(P.PART + 3 * 65536, P.g4, P.b4, (float)(1024 * 16), 256, ssl, t);
  bn_w(P.HB, P.YMIN, ssl, 256, 1024 * 256, wid, t);
  wait_np(np, 3, t);
  knn_w(P.NP3, P.NP4, 64, 16, 256, P.NIDX4, wid, t);
  worker_bar(cnt, 8, t);
  gemm_w(P.NP3, P.HB, P.NP4, P.NIDX4, P.W5, P.HA, P.YMIN, P.PART + 4 * 65536,
         64, 16, 256, 256, 260, 512, wid, t, smem, bslot);
  worker_bar(cnt, 9, t);

  ss_compute(P.PART + 4 * 65536, P.g5, P.b5, (float)(256 * 16), 512, ssl, t);
  bn_w(P.HA, P.YMIN, ssl, 512, 256 * 512, wid, t);
}

__global__ void __launch_bounds__(TPB, 4) mega_kernel(MegaParams P) {
  __shared__ __align__(16) float smem[15872];  // 62 KB union
  int t = threadIdx.x;
  if (blockIdx.x < FB) {
    fps_role(P, smem, blockIdx.x, t);
  } else {
    worker_role(P, smem, blockIdx.x - FB, t, blockIdx.x & 63);
  }
}

// ---------------- classifier head: mean-pool + 3 layers, single block ----------------
__global__ void __launch_bounds__(512) classifier_kernel(
    const float* __restrict__ h4,
    const float* __restrict__ Wc1, const float* __restrict__ bc1,
    const float* __restrict__ gc1, const float* __restrict__ hc1,
    const float* __restrict__ Wc2, const float* __restrict__ bc2,
    const float* __restrict__ gc2, const float* __restrict__ hc2,
    const float* __restrict__ Wc3, const float* __restrict__ bc3,
    float* __restrict__ out) {
  __shared__ float z[16 * 512];
  __shared__ float z1[16 * 256];
  __shared__ float z2[16 * 128];
  __shared__ float sc[256], sh[256];
  int t = threadIdx.x;
  for (int i = t; i < 16 * 512; i += 512) {
    int b = i >> 9, c = i & 511;
    float s = 0.f;
    for (int k = 0; k < 16; k++) s += h4[((size_t)b * 16 + k) * 512 + c];
    z[i] = s * (1.f / 16.f);
  }
  __syncthreads();
  for (int i = t; i < 16 * 256; i += 512) {
    int b = i >> 8, d = i & 255;
    float a = bc1[d];
    for (int c = 0; c < 512; c++) a += z[(b << 9) + c] * Wc1[c * 256 + d];
    z1[i] = a;
  }
  __syncthreads();
  if (t < 256) {
    float s = 0.f, q = 0.f;
    for (int b = 0; b < 16; b++) { float a = z1[(b << 8) + t]; s += a; q += a * a; }
    float mean = s * (1.f / 16.f);
    float var = fmaxf(q * (1.f / 16.f) - mean * mean, 0.f);
    float scl = gc1[t] * rsqrtf(var + BN_EPS);
    sc[t] = scl; sh[t] = hc1[t] - mean * scl;
  }
  __syncthreads();
  for (int i = t; i < 16 * 256; i += 512) {
    int d = i & 255;
    z1[i] = fmaxf(z1[i] * sc[d] + sh[d], 0.f);
  }
  __syncthreads();
  for (int i = t; i < 16 * 128; i += 512) {
    int b = i >> 7, d = i & 127;
    float a = bc2[d];
    for (int c = 0; c < 256; c++) a += z1[(b << 8) + c] * Wc2[c * 128 + d];
    z2[i] = a;
  }
  __syncthreads();
  if (t < 128) {
    float s = 0.f, q = 0.f;
    for (int b = 0; b < 16; b++) { float a = z2[(b << 7) + t]; s += a; q += a * a; }
    float mean = s * (1.f / 16.f);
    float var = fmaxf(q * (1.f / 16.f) - mean * mean, 0.f);
    float scl = gc2[t] * rsqrtf(var + BN_EPS);
    sc[t] = scl; sh[t] = hc2[t] - mean * scl;
  }
  __syncthreads();
  for (int i = t; i < 16 * 128; i += 512) {
    int d = i & 127;
    z2[i] = fmaxf(z2[i] * sc[d] + sh[d], 0.f);
  }
  __syncthreads();
  for (int i = t; i < 640; i += 512) {
    int b = i / 40, d = i % 40;
    float a = bc3[d];
    for (int c = 0; c < 128; c++) a += z2[(b << 7) + c] * Wc3[c * 40 + d];
    out[i] = a;
  }
}

extern "C" void kernel_launch(void* const* d_in, const int* in_sizes, int n_in,
                              void* d_out, int out_size, void* d_ws, size_t ws_size,
                              hipStream_t stream) {
  (void)in_sizes; (void)n_in; (void)out_size; (void)ws_size;
  MegaParams P;
  P.x  = (const float*)d_in[0];
  P.W1 = (const float*)d_in[1];  P.g1 = (const float*)d_in[2];  P.b1 = (const float*)d_in[3];
  P.W2 = (const float*)d_in[4];  P.g2 = (const float*)d_in[5];  P.b2 = (const float*)d_in[6];
  P.W3 = (const float*)d_in[7];  P.g3 = (const float*)d_in[8];  P.b3 = (const float*)d_in[9];
  P.W4 = (const float*)d_in[10]; P.g4 = (const float*)d_in[11]; P.b4 = (const float*)d_in[12];
  P.W5 = (const float*)d_in[13]; P.g5 = (const float*)d_in[14]; P.b5 = (const float*)d_in[15];
  const float* Wc1 = (const float*)d_in[16];
  const float* bc1 = (const float*)d_in[17];
  const float* gc1 = (const float*)d_in[18];
  const float* hc1 = (const float*)d_in[19];
  const float* Wc2 = (const float*)d_in[20];
  const float* bc2 = (const float*)d_in[21];
  const float* gc2 = (const float*)d_in[22];
  const float* hc2 = (const float*)d_in[23];
  const float* Wc3 = (const float*)d_in[24];
  const float* bc3 = (const float*)d_in[25];
  float* out = (float*)d_out;

  float* ws = (float*)d_ws;
  P.HA   = ws;                    // 2,097,152
  P.HB   = P.HA + 2097152;        // 1,048,576
  P.YMIN = P.HB + 1048576;        // 1,048,576
  P.NP1  = P.YMIN + 1048576;      // 49,152
  P.NP2  = P.NP1 + 49152;         // 12,288
  P.NP3  = P.NP2 + 12288;         // 3,072
  P.NP4  = P.NP3 + 3072;          // 768
  P.NIDX1 = (int*)(P.NP4 + 768);      // 262,144 ints
  P.NIDX2 = P.NIDX1 + 262144;         // 65,536
  P.NIDX3 = P.NIDX2 + 65536;          // 16,384
  P.NIDX4 = P.NIDX3 + 16384;          // 4,096
  P.PART  = (float*)(P.NIDX4 + 4096); // 5 * 65,536 floats
  P.SYNC  = (int*)(P.PART + 5 * 65536);  // 32 ints

  // zero PART + SYNC (contiguous) — ws is poisoned 0xAA before every call
  hipMemsetAsync(P.PART, 0, (5 * 65536 + 32) * sizeof(float), stream);

  mega_kernel<<<FB + WB, TPB, 0, stream>>>(P);

  classifier_kernel<<<1, 512, 0, stream>>>(P.HA, Wc1, bc1, gc1, hc1,
                                           Wc2, bc2, gc2, hc2, Wc3, bc3, out);
}

// Round 9
// 1994.320 us; speedup vs baseline: 1.1918x; 1.1918x over previous
//
#include <hip/hip_runtime.h>
#include <math.h>
#include <float.h>

#define BN_EPS 1e-5f
#define WB 240   // worker blocks (blockIdx 16..255)
#define FB 16    // fps blocks   (blockIdx 0..15)
#define TPB 512

// Exact (non-contracted) squared distance: matches numpy mul-then-add order.
__device__ __forceinline__ float sqdist_exact(float dx, float dy, float dz) {
  return __fadd_rn(__fadd_rn(__fmul_rn(dx, dx), __fmul_rn(dy, dy)), __fmul_rn(dz, dz));
}

// Key = (float_bits(dist) << 32) | ~index : max key == max dist, first-index ties.
#define DPP_STEP(CTRL)                                                                   \
  {                                                                                      \
    unsigned int nhi = (unsigned int)__builtin_amdgcn_update_dpp((int)khi, (int)khi,     \
                                                                 CTRL, 0xf, 0xf, false); \
    unsigned int nlo = (unsigned int)__builtin_amdgcn_update_dpp((int)klo, (int)klo,     \
                                                                 CTRL, 0xf, 0xf, false); \
    unsigned long long nk = (((unsigned long long)nhi) << 32) | nlo;                     \
    if (nk > wk) { wk = nk; khi = nhi; klo = nlo; }                                      \
  }

struct MegaParams {
  const float* x;
  const float *W1, *g1, *b1;
  const float *W2, *g2, *b2;
  const float *W3, *g3, *b3;
  const float *W4, *g4, *b4;
  const float *W5, *g5, *b5;
  float *HA, *HB, *YMIN;
  float *NP1, *NP2, *NP3, *NP4;
  int *NIDX1, *NIDX2, *NIDX3, *NIDX4;
  float* PART;  // 5 stages x 65536 floats, 64 slots x 2*D each
  int* SYNC;    // [0..3] np flags, [4..19] barrier counters
};

// Sync primitives: RELAXED polling (no per-iteration L2 invalidate!) with a
// single acquire/release fence at the transition. Agent-scope relaxed atomic
// ops are device-coherent (sc1) but carry no cache-maintenance side effects;
// the acquire fence (one buffer_inv) runs once after the flag flips, and the
// release fence (one L2 writeback) once before publishing. R8's per-poll
// ACQUIRE caused a continuous invalidation storm: 315 MB of L2-miss traffic.
__device__ __forceinline__ void worker_bar(int* cnt, int phase, int t) {
  __syncthreads();  // drain this block's stores
  if (t == 0) {
    __builtin_amdgcn_fence(__ATOMIC_RELEASE, "agent");
    __hip_atomic_fetch_add(&cnt[phase], 1, __ATOMIC_RELAXED, __HIP_MEMORY_SCOPE_AGENT);
    while (__hip_atomic_load(&cnt[phase], __ATOMIC_RELAXED, __HIP_MEMORY_SCOPE_AGENT) < WB)
      __builtin_amdgcn_s_sleep(16);
    __builtin_amdgcn_fence(__ATOMIC_ACQUIRE, "agent");
  }
  __syncthreads();
}

__device__ __forceinline__ void wait_np(int* np, int k, int t) {
  if (t == 0) {
    while (__hip_atomic_load(&np[k], __ATOMIC_RELAXED, __HIP_MEMORY_SCOPE_AGENT) < FB)
      __builtin_amdgcn_s_sleep(16);
    __builtin_amdgcn_fence(__ATOMIC_ACQUIRE, "agent");
  }
  __syncthreads();
}

__device__ __forceinline__ void publish(int* flag) {
  __builtin_amdgcn_fence(__ATOMIC_RELEASE, "agent");
  __hip_atomic_fetch_add(flag, 1, __ATOMIC_RELAXED, __HIP_MEMORY_SCOPE_AGENT);
}

// ---- single-wave FPS (stages 2-4), src points in LDS, coords via readlane ----
template <int PP>
__device__ void fps_w0(const float* src, float* dstG, float* dstL, int lane, int* flag) {
  constexpr int N = PP * 64, M = N / 4;
  float px[PP], py[PP], pz[PP], md[PP];
#pragma unroll
  for (int j = 0; j < PP; j++) {
    int i = j * 64 + lane;
    px[j] = src[3 * i]; py[j] = src[3 * i + 1]; pz[j] = src[3 * i + 2];
    md[j] = INFINITY;
  }
  float lx = src[0], ly = src[1], lz = src[2];
  if (lane == 0) {
    dstG[0] = lx; dstG[1] = ly; dstG[2] = lz;
    if (dstL) { dstL[0] = lx; dstL[1] = ly; dstL[2] = lz; }
  }
  for (int r = 1; r < M; r++) {
    float bv, bx, by, bz; int bi;
    {
      float d0 = sqdist_exact(px[0] - lx, py[0] - ly, pz[0] - lz);
      float m0 = fminf(md[0], d0);
      md[0] = m0;
      bv = m0; bi = lane; bx = px[0]; by = py[0]; bz = pz[0];
    }
#pragma unroll
    for (int j = 1; j < PP; j++) {
      float d = sqdist_exact(px[j] - lx, py[j] - ly, pz[j] - lz);
      float m = fminf(md[j], d);
      md[j] = m;
      if (m > bv) { bv = m; bi = j * 64 + lane; bx = px[j]; by = py[j]; bz = pz[j]; }
    }
    unsigned int khi = __float_as_uint(bv);
    unsigned int klo = ~(unsigned int)bi;
    unsigned long long wk = (((unsigned long long)khi) << 32) | klo;
    DPP_STEP(0x111); DPP_STEP(0x112); DPP_STEP(0x114);
    DPP_STEP(0x118); DPP_STEP(0x142); DPP_STEP(0x143);
    unsigned int wlo = (unsigned int)__builtin_amdgcn_readlane((int)wk, 63);
    int owner = (int)((~wlo) & 63u);
    lx = __int_as_float(__builtin_amdgcn_readlane(__float_as_int(bx), owner));
    ly = __int_as_float(__builtin_amdgcn_readlane(__float_as_int(by), owner));
    lz = __int_as_float(__builtin_amdgcn_readlane(__float_as_int(bz), owner));
    if (lane == 0) {
      dstG[3 * r] = lx; dstG[3 * r + 1] = ly; dstG[3 * r + 2] = lz;
      if (dstL) { dstL[3 * r] = lx; dstL[3 * r + 1] = ly; dstL[3 * r + 2] = lz; }
    }
  }
  if (lane == 0) publish(flag);
}

// ---- FPS role: stage1 = fps4 (measured best), then stages 2-4 on wave 0 ----
__device__ void fps_role(const MegaParams& P, float* smem, int b, int t) {
  constexpr int P1 = 8, BS = 512, N1 = 4096, M1 = 1024;
  float* spts = smem;            // 12288 floats
  float* snew = smem + 12288;    // 3072 floats (NP1 copy)
  unsigned long long* slots = (unsigned long long*)(smem + 15360);  // 16 u64
  const int wv = t >> 6, lane = t & 63;
  const float* pb = P.x + (size_t)b * N1 * 3;
  float px[P1], py[P1], pz[P1], md[P1];
#pragma unroll
  for (int j = 0; j < P1; j++) {
    int i = j * BS + t;
    float xx = pb[3 * i], yy = pb[3 * i + 1], zz = pb[3 * i + 2];
    px[j] = xx; py[j] = yy; pz[j] = zz; md[j] = INFINITY;
    spts[3 * i] = xx; spts[3 * i + 1] = yy; spts[3 * i + 2] = zz;
  }
  float lx = pb[0], ly = pb[1], lz = pb[2];
  if (t == 0) { snew[0] = lx; snew[1] = ly; snew[2] = lz; }

  for (int r = 1; r < M1; r++) {
    float bv; int bi;
    {
      float d0 = sqdist_exact(px[0] - lx, py[0] - ly, pz[0] - lz);
      float m0 = fminf(md[0], d0);
      md[0] = m0;
      bv = m0; bi = t;
    }
#pragma unroll
    for (int j = 1; j < P1; j++) {
      float d = sqdist_exact(px[j] - lx, py[j] - ly, pz[j] - lz);
      float m = fminf(md[j], d);
      md[j] = m;
      if (m > bv) { bv = m; bi = j * BS + t; }
    }
    unsigned int khi = __float_as_uint(bv);
    unsigned int klo = ~(unsigned int)bi;
    unsigned long long wk = (((unsigned long long)khi) << 32) | klo;
    DPP_STEP(0x111); DPP_STEP(0x112); DPP_STEP(0x114);
    DPP_STEP(0x118); DPP_STEP(0x142); DPP_STEP(0x143);
    unsigned long long* base = slots + (r & 1) * 8;
    if (lane == 63) base[wv] = wk;
    __syncthreads();
    unsigned long long fk = base[0];
#pragma unroll
    for (int w = 1; w < 8; w++) {
      unsigned long long k2 = base[w];
      if (k2 > fk) fk = k2;
    }
    unsigned int gidx = ~(unsigned int)fk;
    lx = spts[3 * gidx]; ly = spts[3 * gidx + 1]; lz = spts[3 * gidx + 2];
    if (t == 0) { snew[3 * r] = lx; snew[3 * r + 1] = ly; snew[3 * r + 2] = lz; }
  }
  __syncthreads();
  for (int i = t; i < M1 * 3; i += BS) P.NP1[(size_t)b * M1 * 3 + i] = snew[i];
  __syncthreads();  // drain all waves' NP1 stores
  if (t == 0) publish(&P.SYNC[0]);
  // stages 2-4: wave 0 only, inputs from LDS copies (spts area is dead; snew holds NP1)
  if (t < 64) {
    float* snewB = smem;          // 768 floats (NP2 copy)
    float* snewC = smem + 1024;   // 192 floats (NP3 copy)
    fps_w0<16>(snew, P.NP2 + (size_t)b * 256 * 3, snewB, lane, &P.SYNC[1]);
    fps_w0<4>(snewB, P.NP3 + (size_t)b * 64 * 3, snewC, lane, &P.SYNC[2]);
    fps_w0<1>(snewC, P.NP4 + (size_t)b * 16 * 3, (float*)0, lane, &P.SYNC[3]);
  }
}

// ---- worker: mlp1 + fused per-channel stats ----
__device__ void mlp_w(const MegaParams& P, float* smem, int wid, int t, int bslot) {
  float s = 0.f, q = 0.f;
  int tid0 = wid * TPB + t;
  int d0 = tid0 & 31;
  for (int i = tid0; i < 65536 * 32; i += WB * TPB) {
    int row = i >> 5, d = i & 31;
    float x0 = P.x[row * 3], x1 = P.x[row * 3 + 1], x2 = P.x[row * 3 + 2];
    float a = x0 * P.W1[d] + x1 * P.W1[32 + d] + x2 * P.W1[64 + d];
    P.HA[i] = a; s += a; q += a * a;
  }
  float* sm2 = smem;  // 64 floats
  for (int i = t; i < 64; i += TPB) sm2[i] = 0.f;
  __syncthreads();
  atomicAdd(&sm2[d0], s);
  atomicAdd(&sm2[32 + d0], q);
  __syncthreads();
  for (int i = t; i < 64; i += TPB) atomicAdd(&P.PART[bslot * 64 + i], sm2[i]);
}

// ---- worker: compute BN scale/shift into LDS from PART slots ----
__device__ void ss_compute(const float* partial, const float* g, const float* bb,
                           float cnt, int D, float* ssl, int t) {
  for (int d = t; d < D; d += TPB) {
    float s = 0.f, q = 0.f;
    for (int j = 0; j < 64; j++) { s += partial[j * 2 * D + d]; q += partial[j * 2 * D + D + d]; }
    float mean = s / cnt;
    float var = fmaxf(q / cnt - mean * mean, 0.f);
    float sc = g[d] * rsqrtf(var + BN_EPS);
    ssl[d] = sc; ssl[D + d] = bb[d] - mean * sc;
  }
  __syncthreads();
}

__device__ void bn_w(float* vmax, const float* vmin, const float* ssl, int D, int n,
                     int wid, int t) {
  for (int i = wid * TPB + t; i < n; i += WB * TPB) {
    int d = i & (D - 1);
    float sc = ssl[d], sh = ssl[D + d];
    float v = (sc >= 0.f) ? vmax[i] : vmin[i];
    vmax[i] = fmaxf(v * sc + sh, 0.f);
  }
}

// ---- worker: KNN, one wave per query ----
__device__ void knn_w(const float* p, const float* newp, int N, int M, int BM,
                      int* nidx, int wid, int t) {
  int gw = wid * 8 + (t >> 6);
  int lane = t & 63;
  for (int q = gw; q < BM; q += WB * 8) {
    int b = q / M;
    const float* pb = p + (size_t)b * N * 3;
    float qx = newp[(size_t)q * 3], qy = newp[(size_t)q * 3 + 1], qz = newp[(size_t)q * 3 + 2];
    float bd[16]; int bi[16];
#pragma unroll
    for (int s = 0; s < 16; s++) { bd[s] = INFINITY; bi[s] = 0x7FFFFFFF; }
    for (int c = lane; c < N; c += 64) {
      float d = sqdist_exact(pb[3 * c] - qx, pb[3 * c + 1] - qy, pb[3 * c + 2] - qz);
      if (d < bd[15]) {
        bd[15] = d; bi[15] = c;
#pragma unroll
        for (int s = 15; s >= 1; --s) {
          if (bd[s] < bd[s - 1]) {
            float tf = bd[s]; bd[s] = bd[s - 1]; bd[s - 1] = tf;
            int ti = bi[s]; bi[s] = bi[s - 1]; bi[s - 1] = ti;
          }
        }
      }
    }
    int out = 0;
    for (int r = 0; r < 16; r++) {
      float v = bd[0]; int ii = bi[0];
      float mv = v; int mi = ii;
#pragma unroll
      for (int m = 1; m < 64; m <<= 1) {
        float v2 = __shfl_xor(mv, m);
        int i2 = __shfl_xor(mi, m);
        if (v2 < mv || (v2 == mv && i2 < mi)) { mv = v2; mi = i2; }
      }
      if (mi == ii) {
#pragma unroll
        for (int s = 0; s < 15; s++) { bd[s] = bd[s + 1]; bi[s] = bi[s + 1]; }
        bd[15] = INFINITY; bi[15] = 0x7FFFFFFF;
      }
      if (lane == r) out = mi;
    }
    if (lane < 16) nidx[(size_t)q * 16 + lane] = out;
  }
}

// ---- worker: gather + GEMM + stats + max/min pool ----
__device__ void gemm_w(const float* p, const float* h, const float* newp,
                       const int* nidx, const float* W,
                       float* ymax, float* ymin, float* partial,
                       int N, int M, int BM, int Ch, int Cpad, int D,
                       int wid, int t, float* smem, int bslot) {
  int Ctot = Ch + 3;
  int Gpar = TPB / D;  // D in {64,128,256,512}
  float* sfeat = smem;          // Gpar*16*Cpad <= 4608 floats
  float* sstat = smem + 8192;   // 2*D
  for (int i = t; i < 2 * D; i += TPB) sstat[i] = 0.f;
  int mloc = t / D;
  int d = t % D;
  __syncthreads();
  for (int grp0 = wid * Gpar; grp0 < BM; grp0 += WB * Gpar) {
    int nf = Gpar * 16 * Cpad;
    for (int i = t; i < nf; i += TPB) {
      int c = i % Cpad;
      int rk = i / Cpad;
      int k = rk & 15;
      int g = rk >> 4;
      int grp = grp0 + g;
      float val = 0.f;
      if (grp < BM && c < Ctot) {
        int b = grp / M;
        int nb = nidx[(size_t)grp * 16 + k];
        if (c < 3)
          val = p[((size_t)b * N + nb) * 3 + c] - newp[(size_t)grp * 3 + c];
        else
          val = h[((size_t)b * N + nb) * Ch + (c - 3)];
      }
      sfeat[i] = val;
    }
    __syncthreads();
    int grp = grp0 + mloc;
    bool act = grp < BM;
    const float* fr = sfeat + mloc * 16 * Cpad;
    float acc[16];
#pragma unroll
    for (int k = 0; k < 16; k++) acc[k] = 0.f;
    for (int c = 0; c < Cpad; c += 4) {
      float w0 = (c < Ctot) ? W[(size_t)c * D + d] : 0.f;
      float w1 = (c + 1 < Ctot) ? W[(size_t)(c + 1) * D + d] : 0.f;
      float w2 = (c + 2 < Ctot) ? W[(size_t)(c + 2) * D + d] : 0.f;
      float w3 = (c + 3 < Ctot) ? W[(size_t)(c + 3) * D + d] : 0.f;
#pragma unroll
      for (int k = 0; k < 16; k++) {
        const float4 f = *reinterpret_cast<const float4*>(fr + k * Cpad + c);
        acc[k] += f.x * w0 + f.y * w1 + f.z * w2 + f.w * w3;
      }
    }
    if (act) {
      float ssum = 0.f, ssq = 0.f, amax = -INFINITY, amin = INFINITY;
#pragma unroll
      for (int k = 0; k < 16; k++) {
        float a = acc[k];
        ssum += a; ssq += a * a;
        amax = fmaxf(amax, a); amin = fminf(amin, a);
      }
      ymax[(size_t)grp * D + d] = amax;
      ymin[(size_t)grp * D + d] = amin;
      atomicAdd(&sstat[d], ssum);
      atomicAdd(&sstat[D + d], ssq);
    }
    __syncthreads();
  }
  for (int i = t; i < 2 * D; i += TPB)
    atomicAdd(&partial[bslot * 2 * D + i], sstat[i]);
}

__device__ void worker_role(const MegaParams& P, float* smem, int wid, int t, int bslot) {
  int* np = P.SYNC;
  int* cnt = P.SYNC + 4;
  float* ssl = smem;  // BN scale/shift (<=1024 floats); disjoint phases

  mlp_w(P, smem, wid, t, bslot);
  worker_bar(cnt, 0, t);
  ss_compute(P.PART, P.g1, P.b1, 65536.f, 32, ssl, t);  // count = rows (B*N)
  bn_w(P.HA, P.HA, ssl, 32, 65536 * 32, wid, t);
  worker_bar(cnt, 1, t);

  wait_np(np, 0, t);
  knn_w(P.x, P.NP1, 4096, 1024, 16384, P.NIDX1, wid, t);
  worker_bar(cnt, 2, t);
  gemm_w(P.x, P.HA, P.NP1, P.NIDX1, P.W2, P.HB, P.YMIN, P.PART + 65536,
         4096, 1024, 16384, 32, 36, 64, wid, t, smem, bslot);
  worker_bar(cnt, 3, t);

  ss_compute(P.PART + 65536, P.g2, P.b2, (float)(16384 * 16), 64, ssl, t);
  bn_w(P.HB, P.YMIN, ssl, 64, 16384 * 64, wid, t);
  wait_np(np, 1, t);
  knn_w(P.NP1, P.NP2, 1024, 256, 4096, P.NIDX2, wid, t);
  worker_bar(cnt, 4, t);
  gemm_w(P.NP1, P.HB, P.NP2, P.NIDX2, P.W3, P.HA, P.YMIN, P.PART + 2 * 65536,
         1024, 256, 4096, 64, 68, 128, wid, t, smem, bslot);
  worker_bar(cnt, 5, t);

  ss_compute(P.PART + 2 * 65536, P.g3, P.b3, (float)(4096 * 16), 128, ssl, t);
  bn_w(P.HA, P.YMIN, ssl, 128, 4096 * 128, wid, t);
  wait_np(np, 2, t);
  knn_w(P.NP2, P.NP3, 256, 64, 1024, P.NIDX3, wid, t);
  worker_bar(cnt, 6, t);
  gemm_w(P.NP2, P.HA, P.NP3, P.NIDX3, P.W4, P.HB, P.YMIN, P.PART + 3 * 65536,
         256, 64, 1024, 128, 132, 256, wid, t, smem, bslot);
  worker_bar(cnt, 7, t);

  ss_compute(P.PART + 3 * 65536, P.g4, P.b4, (float)(1024 * 16), 256, ssl, t);
  bn_w(P.HB, P.YMIN, ssl, 256, 1024 * 256, wid, t);
  wait_np(np, 3, t);
  knn_w(P.NP3, P.NP4, 64, 16, 256, P.NIDX4, wid, t);
  worker_bar(cnt, 8, t);
  gemm_w(P.NP3, P.HB, P.NP4, P.NIDX4, P.W5, P.HA, P.YMIN, P.PART + 4 * 65536,
         64, 16, 256, 256, 260, 512, wid, t, smem, bslot);
  worker_bar(cnt, 9, t);

  ss_compute(P.PART + 4 * 65536, P.g5, P.b5, (float)(256 * 16), 512, ssl, t);
  bn_w(P.HA, P.YMIN, ssl, 512, 256 * 512, wid, t);
}

__global__ void __launch_bounds__(TPB, 4) mega_kernel(MegaParams P) {
  __shared__ __align__(16) float smem[15872];  // 62 KB union
  int t = threadIdx.x;
  if (blockIdx.x < FB) {
    fps_role(P, smem, blockIdx.x, t);
  } else {
    worker_role(P, smem, blockIdx.x - FB, t, blockIdx.x & 63);
  }
}

// ---------------- classifier head: mean-pool + 3 layers, single block ----------------
__global__ void __launch_bounds__(512) classifier_kernel(
    const float* __restrict__ h4,
    const float* __restrict__ Wc1, const float* __restrict__ bc1,
    const float* __restrict__ gc1, const float* __restrict__ hc1,
    const float* __restrict__ Wc2, const float* __restrict__ bc2,
    const float* __restrict__ gc2, const float* __restrict__ hc2,
    const float* __restrict__ Wc3, const float* __restrict__ bc3,
    float* __restrict__ out) {
  __shared__ float z[16 * 512];
  __shared__ float z1[16 * 256];
  __shared__ float z2[16 * 128];
  __shared__ float sc[256], sh[256];
  int t = threadIdx.x;
  for (int i = t; i < 16 * 512; i += 512) {
    int b = i >> 9, c = i & 511;
    float s = 0.f;
    for (int k = 0; k < 16; k++) s += h4[((size_t)b * 16 + k) * 512 + c];
    z[i] = s * (1.f / 16.f);
  }
  __syncthreads();
  for (int i = t; i < 16 * 256; i += 512) {
    int b = i >> 8, d = i & 255;
    float a = bc1[d];
    for (int c = 0; c < 512; c++) a += z[(b << 9) + c] * Wc1[c * 256 + d];
    z1[i] = a;
  }
  __syncthreads();
  if (t < 256) {
    float s = 0.f, q = 0.f;
    for (int b = 0; b < 16; b++) { float a = z1[(b << 8) + t]; s += a; q += a * a; }
    float mean = s * (1.f / 16.f);
    float var = fmaxf(q * (1.f / 16.f) - mean * mean, 0.f);
    float scl = gc1[t] * rsqrtf(var + BN_EPS);
    sc[t] = scl; sh[t] = hc1[t] - mean * scl;
  }
  __syncthreads();
  for (int i = t; i < 16 * 256; i += 512) {
    int d = i & 255;
    z1[i] = fmaxf(z1[i] * sc[d] + sh[d], 0.f);
  }
  __syncthreads();
  for (int i = t; i < 16 * 128; i += 512) {
    int b = i >> 7, d = i & 127;
    float a = bc2[d];
    for (int c = 0; c < 256; c++) a += z1[(b << 8) + c] * Wc2[c * 128 + d];
    z2[i] = a;
  }
  __syncthreads();
  if (t < 128) {
    float s = 0.f, q = 0.f;
    for (int b = 0; b < 16; b++) { float a = z2[(b << 7) + t]; s += a; q += a * a; }
    float mean = s * (1.f / 16.f);
    float var = fmaxf(q * (1.f / 16.f) - mean * mean, 0.f);
    float scl = gc2[t] * rsqrtf(var + BN_EPS);
    sc[t] = scl; sh[t] = hc2[t] - mean * scl;
  }
  __syncthreads();
  for (int i = t; i < 16 * 128; i += 512) {
    int d = i & 127;
    z2[i] = fmaxf(z2[i] * sc[d] + sh[d], 0.f);
  }
  __syncthreads();
  for (int i = t; i < 640; i += 512) {
    int b = i / 40, d = i % 40;
    float a = bc3[d];
    for (int c = 0; c < 128; c++) a += z2[(b << 7) + c] * Wc3[c * 40 + d];
    out[i] = a;
  }
}

extern "C" void kernel_launch(void* const* d_in, const int* in_sizes, int n_in,
                              void* d_out, int out_size, void* d_ws, size_t ws_size,
                              hipStream_t stream) {
  (void)in_sizes; (void)n_in; (void)out_size; (void)ws_size;
  MegaParams P;
  P.x  = (const float*)d_in[0];
  P.W1 = (const float*)d_in[1];  P.g1 = (const float*)d_in[2];  P.b1 = (const float*)d_in[3];
  P.W2 = (const float*)d_in[4];  P.g2 = (const float*)d_in[5];  P.b2 = (const float*)d_in[6];
  P.W3 = (const float*)d_in[7];  P.g3 = (const float*)d_in[8];  P.b3 = (const float*)d_in[9];
  P.W4 = (const float*)d_in[10]; P.g4 = (const float*)d_in[11]; P.b4 = (const float*)d_in[12];
  P.W5 = (const float*)d_in[13]; P.g5 = (const float*)d_in[14]; P.b5 = (const float*)d_in[15];
  const float* Wc1 = (const float*)d_in[16];
  const float* bc1 = (const float*)d_in[17];
  const float* gc1 = (const float*)d_in[18];
  const float* hc1 = (const float*)d_in[19];
  const float* Wc2 = (const float*)d_in[20];
  const float* bc2 = (const float*)d_in[21];
  const float* gc2 = (const float*)d_in[22];
  const float* hc2 = (const float*)d_in[23];
  const float* Wc3 = (const float*)d_in[24];
  const float* bc3 = (const float*)d_in[25];
  float* out = (float*)d_out;

  float* ws = (float*)d_ws;
  P.HA   = ws;                    // 2,097,152
  P.HB   = P.HA + 2097152;        // 1,048,576
  P.YMIN = P.HB + 1048576;        // 1,048,576
  P.NP1  = P.YMIN + 1048576;      // 49,152
  P.NP2  = P.NP1 + 49152;         // 12,288
  P.NP3  = P.NP2 + 12288;         // 3,072
  P.NP4  = P.NP3 + 3072;          // 768
  P.NIDX1 = (int*)(P.NP4 + 768);      // 262,144 ints
  P.NIDX2 = P.NIDX1 + 262144;         // 65,536
  P.NIDX3 = P.NIDX2 + 65536;          // 16,384
  P.NIDX4 = P.NIDX3 + 16384;          // 4,096
  P.PART  = (float*)(P.NIDX4 + 4096); // 5 * 65,536 floats
  P.SYNC  = (int*)(P.PART + 5 * 65536);  // 32 ints

  // zero PART + SYNC (contiguous) — ws is poisoned 0xAA before every call
  hipMemsetAsync(P.PART, 0, (5 * 65536 + 32) * sizeof(float), stream);

  mega_kernel<<<FB + WB, TPB, 0, stream>>>(P);

  classifier_kernel<<<1, 512, 0, stream>>>(P.HA, Wc1, bc1, gc1, hc1,
                                           Wc2, bc2, gc2, hc2, Wc3, bc3, out);
}